// Round 1
// baseline (482.526 us; speedup 1.0000x reference)
//
#include <hip/hip_runtime.h>

// 2-layer GCN collapsed to scalar per-node quantities (verified R2):
//   dis = 1/sqrt(deg+1);  y = x*dis;  t[d] = sum_{e->d} y[src]
//   s = dis*(t+y);  z = dis * sum_j relu(s*W1[j]+b1[j])*W2[j]
//   out[d] = dis[d]*(sum_{e->d} z[src] + z[d]) + b2
//
// R13: fuse the three node kernels (prep1/prep2/finout) into their preceding
// aggregation kernels via last-block-done per bucket (agent-scope counter +
// release/acquire fences). Dispatches 8 -> 5; partial rows consumed L2-hot.
// part_k and the aggregation bodies are byte-identical to R12.

#define SB_BITS 11
#define SBK     2048          // nodes per bucket
#define MAXB    64            // bucket bound (N <= 131072)
#define TBP     256           // part_k block size
#define NAPB    1024          // part_k grid (1 tile/block)
#define TPT     4096          // part_k tile (16 edges/thread)
#define KPT     16
#define NW      4             // waves per part_k block
#define NSET    16            // independent cursor/region sets
#define GSTRIDE 8             // u32 stride between cursors (32B granule)
#define RSL     16            // partial rows per bucket (= NSET)
#define TBA     256           // aggregation block size

__device__ inline void lds_addf(float* p, float v) {
    __hip_atomic_fetch_add(p, v, __ATOMIC_RELAXED, __HIP_MEMORY_SCOPE_WORKGROUP);
}

// last-block-done claim: returns 1 for exactly the final block of a bucket.
__device__ inline int claim_last(unsigned* c) {
    __shared__ int lastf;
    __threadfence();              // release: partial-row stores -> agent scope
    __syncthreads();
    if (threadIdx.x == 0)
        lastf = ((int)__hip_atomic_fetch_add(c, 1u, __ATOMIC_ACQ_REL,
                                             __HIP_MEMORY_SCOPE_AGENT) == NSET - 1);
    __syncthreads();
    if (!lastf) return 0;
    __threadfence();              // acquire: see other blocks' partial rows
    return 1;
}

// ---------------- K1: partition ----------------
__global__ __launch_bounds__(TBP) void part_k(
        const int* __restrict__ src, const int* __restrict__ dst, int E,
        int cap, int capS, unsigned* __restrict__ gcur,
        unsigned* __restrict__ packedB) {
    __shared__ unsigned sp[TPT];
    __shared__ unsigned char sbk[TPT];
    __shared__ unsigned woff[NW][MAXB];
    __shared__ unsigned cnt2[NW][MAXB];
    __shared__ unsigned scn[MAXB];
    __shared__ unsigned gbase[MAXB];
    const int t = threadIdx.x;
    const int w = t >> 6;
    const int lane = t & 63;
    const int set = blockIdx.x & (NSET - 1);
    int CH = (E + (int)gridDim.x - 1) / (int)gridDim.x;
    int cs = blockIdx.x * CH;
    int ce = min(cs + CH, E);
    for (int ts = cs; ts < ce; ts += TPT) {
        int tcnt = min(TPT, ce - ts);
        if (t < MAXB) {
            #pragma unroll
            for (int ww = 0; ww < NW; ww++) { woff[ww][t] = 0u; cnt2[ww][t] = 0u; }
        }
        __syncthreads();
        unsigned es[KPT], ed[KPT]; int nk = 0;
        #pragma unroll
        for (int k = 0; k < KPT; k++) {
            int j = ts + t + k * TBP;
            if (j < ce) {
                es[k] = (unsigned)src[j];
                ed[k] = (unsigned)dst[j];
                atomicAdd(&woff[w][ed[k] >> SB_BITS], 1u);
                nk = k + 1;
            }
        }
        __syncthreads();
        if (t < MAXB) {
            unsigned h0 = woff[0][t], h1 = woff[1][t], h2 = woff[2][t], h3 = woff[3][t];
            woff[0][t] = 0u; woff[1][t] = h0; woff[2][t] = h0 + h1;
            woff[3][t] = h0 + h1 + h2;
            unsigned th = h0 + h1 + h2 + h3;
            gbase[t] = th ? atomicAdd(&gcur[(t * NSET + set) * GSTRIDE], th) : 0u;
            unsigned v = th;
            #pragma unroll
            for (int off = 1; off < 64; off <<= 1) {
                unsigned u = __shfl_up(v, off, 64);
                if (lane >= off) v += u;
            }
            scn[t] = v - th;
        }
        __syncthreads();
        for (int k = 0; k < nk; k++) {
            unsigned b = ed[k] >> SB_BITS;
            unsigned r = scn[b] + woff[w][b] + atomicAdd(&cnt2[w][b], 1u);
            sp[r]  = es[k] | ((ed[k] & (SBK - 1u)) << 17);
            sbk[r] = (unsigned char)b;
        }
        __syncthreads();
        #pragma unroll
        for (int k = 0; k < KPT; k++) {
            int j2 = t + k * TBP;
            if (j2 < tcnt) {
                unsigned b = sbk[j2];
                unsigned gpos = gbase[b] + (unsigned)j2 - scn[b];
                if (gpos < (unsigned)capS)
                    packedB[(size_t)b * cap + (size_t)set * capS + gpos] = sp[j2];
            }
        }
        __syncthreads();
    }
}

// ---------------- K2: degree partials + fused prep1 (dis, y) ----------------
__global__ __launch_bounds__(TBA) void degp_k(
        const unsigned* __restrict__ packedB, const unsigned* __restrict__ gcur,
        int cap, int capS, int PLN, unsigned* __restrict__ dpart,
        unsigned* __restrict__ ctr, const float* __restrict__ x, int N,
        float* __restrict__ dis, float* __restrict__ y) {
    __shared__ unsigned acc[SBK];
    for (int i = threadIdx.x; i < SBK; i += TBA) acc[i] = 0u;
    __syncthreads();
    int b = blockIdx.x >> 4, set = blockIdx.x & 15;
    unsigned cnt = min(gcur[(b * NSET + set) * GSTRIDE], (unsigned)capS);
    const unsigned* p = packedB + (size_t)b * cap + (size_t)set * capS;
    const uint4* p4 = (const uint4*)p;
    unsigned nq = cnt >> 2;
    unsigned qi = threadIdx.x;
    for (; qi + TBA < nq; qi += 2 * TBA) {
        uint4 a = p4[qi], c = p4[qi + TBA];
        atomicAdd(&acc[a.x >> 17], 1u); atomicAdd(&acc[a.y >> 17], 1u);
        atomicAdd(&acc[a.z >> 17], 1u); atomicAdd(&acc[a.w >> 17], 1u);
        atomicAdd(&acc[c.x >> 17], 1u); atomicAdd(&acc[c.y >> 17], 1u);
        atomicAdd(&acc[c.z >> 17], 1u); atomicAdd(&acc[c.w >> 17], 1u);
    }
    for (; qi < nq; qi += TBA) {
        uint4 a = p4[qi];
        atomicAdd(&acc[a.x >> 17], 1u); atomicAdd(&acc[a.y >> 17], 1u);
        atomicAdd(&acc[a.z >> 17], 1u); atomicAdd(&acc[a.w >> 17], 1u);
    }
    for (unsigned j = (nq << 2) + threadIdx.x; j < cnt; j += TBA)
        atomicAdd(&acc[p[j] >> 17], 1u);
    __syncthreads();
    unsigned* o = dpart + (size_t)set * PLN + (size_t)b * SBK;
    for (int i = threadIdx.x; i < SBK; i += TBA) o[i] = acc[i];

    // ---- fused prep1: last block of this bucket computes dis,y ----
    if (!claim_last(&ctr[b])) return;
    int base = b << SB_BITS;
    for (int i = threadIdx.x; i < SBK; i += TBA) {
        int gi = base + i;
        if (gi < N) {
            unsigned d = 1u;   // self loop
            #pragma unroll
            for (int r = 0; r < RSL; r++) d += dpart[(size_t)r * PLN + gi];
            float rr = 1.0f / sqrtf((float)d);
            dis[gi] = rr;
            y[gi] = x[gi] * rr;
        }
    }
}

// ---------------- K3: gather y partials + fused prep2 (z) ----------------
__global__ __launch_bounds__(TBA) void gacc1_k(
        const unsigned* __restrict__ packedB, const unsigned* __restrict__ gcur,
        const float* __restrict__ val /* y */, int cap, int capS, int PLN,
        float* __restrict__ fpart, unsigned* __restrict__ ctr,
        const float* __restrict__ dis,
        const float* __restrict__ W1, const float* __restrict__ b1,
        const float* __restrict__ W2, float* __restrict__ z, int N) {
    __shared__ float acc[SBK];
    __shared__ float sW1[256], sb1[256], sW2[256];
    for (int i = threadIdx.x; i < SBK; i += TBA) acc[i] = 0.0f;
    __syncthreads();
    int b = blockIdx.x >> 4, set = blockIdx.x & 15;
    unsigned cnt = min(gcur[(b * NSET + set) * GSTRIDE], (unsigned)capS);
    const unsigned* p = packedB + (size_t)b * cap + (size_t)set * capS;
    const uint4* p4 = (const uint4*)p;
    unsigned nq = cnt >> 2;
    unsigned qi = threadIdx.x;
    for (; qi + TBA < nq; qi += 2 * TBA) {
        uint4 a = p4[qi], c = p4[qi + TBA];
        float v0 = val[a.x & 0x1FFFFu], v1 = val[a.y & 0x1FFFFu];
        float v2 = val[a.z & 0x1FFFFu], v3 = val[a.w & 0x1FFFFu];
        float v4 = val[c.x & 0x1FFFFu], v5 = val[c.y & 0x1FFFFu];
        float v6 = val[c.z & 0x1FFFFu], v7 = val[c.w & 0x1FFFFu];
        lds_addf(&acc[a.x >> 17], v0); lds_addf(&acc[a.y >> 17], v1);
        lds_addf(&acc[a.z >> 17], v2); lds_addf(&acc[a.w >> 17], v3);
        lds_addf(&acc[c.x >> 17], v4); lds_addf(&acc[c.y >> 17], v5);
        lds_addf(&acc[c.z >> 17], v6); lds_addf(&acc[c.w >> 17], v7);
    }
    for (; qi < nq; qi += TBA) {
        uint4 a = p4[qi];
        float v0 = val[a.x & 0x1FFFFu], v1 = val[a.y & 0x1FFFFu];
        float v2 = val[a.z & 0x1FFFFu], v3 = val[a.w & 0x1FFFFu];
        lds_addf(&acc[a.x >> 17], v0); lds_addf(&acc[a.y >> 17], v1);
        lds_addf(&acc[a.z >> 17], v2); lds_addf(&acc[a.w >> 17], v3);
    }
    for (unsigned j = (nq << 2) + threadIdx.x; j < cnt; j += TBA) {
        unsigned pk = p[j];
        lds_addf(&acc[pk >> 17], val[pk & 0x1FFFFu]);
    }
    __syncthreads();
    float* o = fpart + (size_t)set * PLN + (size_t)b * SBK;
    for (int i = threadIdx.x; i < SBK; i += TBA) o[i] = acc[i];

    // ---- fused prep2: last block of this bucket computes z ----
    if (!claim_last(&ctr[b])) return;
    for (int j = threadIdx.x; j < 256; j += TBA) {
        sW1[j] = W1[j]; sb1[j] = b1[j]; sW2[j] = W2[j];
    }
    __syncthreads();
    const float4* w1v = (const float4*)sW1;
    const float4* b1v = (const float4*)sb1;
    const float4* w2v = (const float4*)sW2;
    int base = b << SB_BITS;
    for (int i = threadIdx.x; i < SBK; i += TBA) {
        int gi = base + i;
        if (gi < N) {
            float tt = 0.0f;
            #pragma unroll
            for (int r = 0; r < RSL; r++) tt += fpart[(size_t)r * PLN + gi];
            float rr = dis[gi];
            float s = rr * (tt + val[gi]);
            float g = 0.0f;
            #pragma unroll 8
            for (int jj = 0; jj < 64; jj++) {   // H=256 -> 64 quads
                float4 a = w1v[jj], bb = b1v[jj], c = w2v[jj];
                float h0 = fmaf(s, a.x, bb.x); h0 = h0 > 0.0f ? h0 : 0.0f;
                float h1 = fmaf(s, a.y, bb.y); h1 = h1 > 0.0f ? h1 : 0.0f;
                float h2 = fmaf(s, a.z, bb.z); h2 = h2 > 0.0f ? h2 : 0.0f;
                float h3 = fmaf(s, a.w, bb.w); h3 = h3 > 0.0f ? h3 : 0.0f;
                g = fmaf(h0, c.x, g); g = fmaf(h1, c.y, g);
                g = fmaf(h2, c.z, g); g = fmaf(h3, c.w, g);
            }
            z[gi] = g * rr;
        }
    }
}

// ---------------- K4: gather z partials + fused finout ----------------
__global__ __launch_bounds__(TBA) void gacc2_k(
        const unsigned* __restrict__ packedB, const unsigned* __restrict__ gcur,
        const float* __restrict__ val /* z */, int cap, int capS, int PLN,
        float* __restrict__ fpart, unsigned* __restrict__ ctr,
        const float* __restrict__ dis, const float* __restrict__ b2,
        float* __restrict__ out, int N) {
    __shared__ float acc[SBK];
    for (int i = threadIdx.x; i < SBK; i += TBA) acc[i] = 0.0f;
    __syncthreads();
    int b = blockIdx.x >> 4, set = blockIdx.x & 15;
    unsigned cnt = min(gcur[(b * NSET + set) * GSTRIDE], (unsigned)capS);
    const unsigned* p = packedB + (size_t)b * cap + (size_t)set * capS;
    const uint4* p4 = (const uint4*)p;
    unsigned nq = cnt >> 2;
    unsigned qi = threadIdx.x;
    for (; qi + TBA < nq; qi += 2 * TBA) {
        uint4 a = p4[qi], c = p4[qi + TBA];
        float v0 = val[a.x & 0x1FFFFu], v1 = val[a.y & 0x1FFFFu];
        float v2 = val[a.z & 0x1FFFFu], v3 = val[a.w & 0x1FFFFu];
        float v4 = val[c.x & 0x1FFFFu], v5 = val[c.y & 0x1FFFFu];
        float v6 = val[c.z & 0x1FFFFu], v7 = val[c.w & 0x1FFFFu];
        lds_addf(&acc[a.x >> 17], v0); lds_addf(&acc[a.y >> 17], v1);
        lds_addf(&acc[a.z >> 17], v2); lds_addf(&acc[a.w >> 17], v3);
        lds_addf(&acc[c.x >> 17], v4); lds_addf(&acc[c.y >> 17], v5);
        lds_addf(&acc[c.z >> 17], v6); lds_addf(&acc[c.w >> 17], v7);
    }
    for (; qi < nq; qi += TBA) {
        uint4 a = p4[qi];
        float v0 = val[a.x & 0x1FFFFu], v1 = val[a.y & 0x1FFFFu];
        float v2 = val[a.z & 0x1FFFFu], v3 = val[a.w & 0x1FFFFu];
        lds_addf(&acc[a.x >> 17], v0); lds_addf(&acc[a.y >> 17], v1);
        lds_addf(&acc[a.z >> 17], v2); lds_addf(&acc[a.w >> 17], v3);
    }
    for (unsigned j = (nq << 2) + threadIdx.x; j < cnt; j += TBA) {
        unsigned pk = p[j];
        lds_addf(&acc[pk >> 17], val[pk & 0x1FFFFu]);
    }
    __syncthreads();
    float* o = fpart + (size_t)set * PLN + (size_t)b * SBK;
    for (int i = threadIdx.x; i < SBK; i += TBA) o[i] = acc[i];

    // ---- fused finout: last block of this bucket writes out ----
    if (!claim_last(&ctr[b])) return;
    float bb2 = b2[0];
    int base = b << SB_BITS;
    for (int i = threadIdx.x; i < SBK; i += TBA) {
        int gi = base + i;
        if (gi < N) {
            float u = 0.0f;
            #pragma unroll
            for (int r = 0; r < RSL; r++) u += fpart[(size_t)r * PLN + gi];
            out[gi] = dis[gi] * (u + val[gi]) + bb2;
        }
    }
}

extern "C" void kernel_launch(void* const* d_in, const int* in_sizes, int n_in,
                              void* d_out, int out_size, void* d_ws, size_t ws_size,
                              hipStream_t stream) {
    const float* x   = (const float*)d_in[0];
    const int*   ei  = (const int*)d_in[1];     // int32 (JAX x64-off)
    const float* W1  = (const float*)d_in[2];
    const float* b1  = (const float*)d_in[3];
    const float* W2  = (const float*)d_in[4];
    const float* b2  = (const float*)d_in[5];
    float*       out = (float*)d_out;

    const int N = in_sizes[0];        // 100000
    const int E = in_sizes[1] / 2;    // 3200000

    const int* srcp = ei;
    const int* dstp = ei + E;

    const int NB   = (N + SBK - 1) >> SB_BITS;              // 49
    const int PLN  = NB * SBK;                              // 100352
    const int capS = (E / (NB * NSET) + 1536 + 7) & ~7;     // ~24 sigma, 8-aligned
    const int cap  = capS * NSET;

    // workspace (u32 units):
    // [gcur 8192][ctr 256][dis N][y N][z N][part RSL*PLN][packedB NB*cap]
    unsigned* W    = (unsigned*)d_ws;
    unsigned* gcur = W;
    unsigned* ctr  = W + 8192;                                // 3 stages x 64
    float*    dis  = (float*)(W + 8448);
    float*    y    = (float*)(W + 8448 + (size_t)N);
    float*    z    = (float*)(W + 8448 + (size_t)2 * N);
    unsigned* part = W + 8448 + (size_t)3 * N;                // RSL*PLN
    unsigned* packedB = part + (size_t)RSL * PLN;             // NB*cap (16B-aligned)

    hipMemsetAsync(gcur, 0, 8448 * sizeof(unsigned), stream);

    const int gA = NB * NSET;   // 784

    part_k <<<NAPB, TBP, 0, stream>>>(srcp, dstp, E, cap, capS, gcur, packedB);
    degp_k <<<gA, TBA, 0, stream>>>(packedB, gcur, cap, capS, PLN, part,
                                    ctr, x, N, dis, y);
    gacc1_k<<<gA, TBA, 0, stream>>>(packedB, gcur, y, cap, capS, PLN,
                                    (float*)part, ctr + 64, dis, W1, b1, W2, z, N);
    gacc2_k<<<gA, TBA, 0, stream>>>(packedB, gcur, z, cap, capS, PLN,
                                    (float*)part, ctr + 128, dis, b2, out, N);
}

// Round 2
// 203.634 us; speedup vs baseline: 2.3696x; 2.3696x over previous
//
#include <hip/hip_runtime.h>

// 2-layer GCN collapsed to scalar per-node quantities (verified R2):
//   dis = 1/sqrt(deg+1);  y = x*dis;  t[d] = sum_{e->d} y[src]
//   s = dis*(t+y);  z = dis * sum_j relu(s*W1[j]+b1[j])*W2[j]
//   out[d] = dis[d]*(sum_{e->d} z[src] + z[d]) + b2
//
// R14: keep R13's last-block-done fusion (5 dispatches) but fix the fence
// catastrophe. R13 used __threadfence() in every block -> full L2
// writeback/invalidate x784 blocks x3 kernels (gacc1_k 178us, VALUBusy 1.7%).
// R14: no partial rows at all. Aggregation blocks atomicAdd (device scope,
// performed at the coherent point -> no dirty L2, no fence) into a single
// per-node total row. Release = the vmcnt drain __syncthreads already emits;
// claim counter = relaxed device-scope atomicAdd; last block reads totals
// via relaxed agent-scope atomic loads. part_k unchanged.

#define SB_BITS 11
#define SBK     2048          // nodes per bucket
#define MAXB    64            // bucket bound (N <= 131072)
#define TBP     256           // part_k block size
#define NAPB    1024          // part_k grid (1 tile/block)
#define TPT     4096          // part_k tile (16 edges/thread)
#define KPT     16
#define NW      4             // waves per part_k block
#define NSET    16            // independent cursor/region sets
#define GSTRIDE 8             // u32 stride between cursors (32B granule)
#define TBA     256           // aggregation block size

__device__ inline void lds_addf(float* p, float v) {
    __hip_atomic_fetch_add(p, v, __ATOMIC_RELAXED, __HIP_MEMORY_SCOPE_WORKGROUP);
}

__device__ inline unsigned agent_ld_u(const unsigned* p) {
    return __hip_atomic_load(p, __ATOMIC_RELAXED, __HIP_MEMORY_SCOPE_AGENT);
}
__device__ inline float agent_ld_f(const float* p) {
    return __hip_atomic_load(p, __ATOMIC_RELAXED, __HIP_MEMORY_SCOPE_AGENT);
}

// last-block-done claim. Preceding __syncthreads drains every wave's
// outstanding vmem ops (compiler emits s_waitcnt vmcnt(0) before s_barrier),
// so all this block's device-scope atomics are globally performed before the
// counter bump. No cache maintenance needed: nothing dirty in L2.
__device__ inline int claim_last(unsigned* c) {
    __shared__ int lastf;
    asm volatile("s_waitcnt vmcnt(0)" ::: "memory");
    __syncthreads();
    if (threadIdx.x == 0)
        lastf = (atomicAdd(c, 1u) == NSET - 1u);
    __syncthreads();
    return lastf;
}

// ---------------- K1: partition ----------------
__global__ __launch_bounds__(TBP) void part_k(
        const int* __restrict__ src, const int* __restrict__ dst, int E,
        int cap, int capS, unsigned* __restrict__ gcur,
        unsigned* __restrict__ packedB) {
    __shared__ unsigned sp[TPT];
    __shared__ unsigned char sbk[TPT];
    __shared__ unsigned woff[NW][MAXB];
    __shared__ unsigned cnt2[NW][MAXB];
    __shared__ unsigned scn[MAXB];
    __shared__ unsigned gbase[MAXB];
    const int t = threadIdx.x;
    const int w = t >> 6;
    const int lane = t & 63;
    const int set = blockIdx.x & (NSET - 1);
    int CH = (E + (int)gridDim.x - 1) / (int)gridDim.x;
    int cs = blockIdx.x * CH;
    int ce = min(cs + CH, E);
    for (int ts = cs; ts < ce; ts += TPT) {
        int tcnt = min(TPT, ce - ts);
        if (t < MAXB) {
            #pragma unroll
            for (int ww = 0; ww < NW; ww++) { woff[ww][t] = 0u; cnt2[ww][t] = 0u; }
        }
        __syncthreads();
        unsigned es[KPT], ed[KPT]; int nk = 0;
        #pragma unroll
        for (int k = 0; k < KPT; k++) {
            int j = ts + t + k * TBP;
            if (j < ce) {
                es[k] = (unsigned)src[j];
                ed[k] = (unsigned)dst[j];
                atomicAdd(&woff[w][ed[k] >> SB_BITS], 1u);
                nk = k + 1;
            }
        }
        __syncthreads();
        if (t < MAXB) {
            unsigned h0 = woff[0][t], h1 = woff[1][t], h2 = woff[2][t], h3 = woff[3][t];
            woff[0][t] = 0u; woff[1][t] = h0; woff[2][t] = h0 + h1;
            woff[3][t] = h0 + h1 + h2;
            unsigned th = h0 + h1 + h2 + h3;
            gbase[t] = th ? atomicAdd(&gcur[(t * NSET + set) * GSTRIDE], th) : 0u;
            unsigned v = th;
            #pragma unroll
            for (int off = 1; off < 64; off <<= 1) {
                unsigned u = __shfl_up(v, off, 64);
                if (lane >= off) v += u;
            }
            scn[t] = v - th;
        }
        __syncthreads();
        for (int k = 0; k < nk; k++) {
            unsigned b = ed[k] >> SB_BITS;
            unsigned r = scn[b] + woff[w][b] + atomicAdd(&cnt2[w][b], 1u);
            sp[r]  = es[k] | ((ed[k] & (SBK - 1u)) << 17);
            sbk[r] = (unsigned char)b;
        }
        __syncthreads();
        #pragma unroll
        for (int k = 0; k < KPT; k++) {
            int j2 = t + k * TBP;
            if (j2 < tcnt) {
                unsigned b = sbk[j2];
                unsigned gpos = gbase[b] + (unsigned)j2 - scn[b];
                if (gpos < (unsigned)capS)
                    packedB[(size_t)b * cap + (size_t)set * capS + gpos] = sp[j2];
            }
        }
        __syncthreads();
    }
}

// ---------------- K2: degree totals + fused prep1 (dis, y) ----------------
__global__ __launch_bounds__(TBA) void degp_k(
        const unsigned* __restrict__ packedB, const unsigned* __restrict__ gcur,
        int cap, int capS, unsigned* __restrict__ tdeg,
        unsigned* __restrict__ ctr, const float* __restrict__ x, int N,
        float* __restrict__ dis, float* __restrict__ y) {
    __shared__ unsigned acc[SBK];
    for (int i = threadIdx.x; i < SBK; i += TBA) acc[i] = 0u;
    __syncthreads();
    int b = blockIdx.x >> 4, set = blockIdx.x & 15;
    unsigned cnt = min(gcur[(b * NSET + set) * GSTRIDE], (unsigned)capS);
    const unsigned* p = packedB + (size_t)b * cap + (size_t)set * capS;
    const uint4* p4 = (const uint4*)p;
    unsigned nq = cnt >> 2;
    unsigned qi = threadIdx.x;
    for (; qi + TBA < nq; qi += 2 * TBA) {
        uint4 a = p4[qi], c = p4[qi + TBA];
        atomicAdd(&acc[a.x >> 17], 1u); atomicAdd(&acc[a.y >> 17], 1u);
        atomicAdd(&acc[a.z >> 17], 1u); atomicAdd(&acc[a.w >> 17], 1u);
        atomicAdd(&acc[c.x >> 17], 1u); atomicAdd(&acc[c.y >> 17], 1u);
        atomicAdd(&acc[c.z >> 17], 1u); atomicAdd(&acc[c.w >> 17], 1u);
    }
    for (; qi < nq; qi += TBA) {
        uint4 a = p4[qi];
        atomicAdd(&acc[a.x >> 17], 1u); atomicAdd(&acc[a.y >> 17], 1u);
        atomicAdd(&acc[a.z >> 17], 1u); atomicAdd(&acc[a.w >> 17], 1u);
    }
    for (unsigned j = (nq << 2) + threadIdx.x; j < cnt; j += TBA)
        atomicAdd(&acc[p[j] >> 17], 1u);
    __syncthreads();
    int base = b << SB_BITS;
    for (int i = threadIdx.x; i < SBK; i += TBA) {
        unsigned v = acc[i];
        if (v) atomicAdd(&tdeg[base + i], v);   // device scope, coherent point
    }

    // ---- fused prep1: last block of this bucket computes dis,y ----
    if (!claim_last(&ctr[b])) return;
    for (int i = threadIdx.x; i < SBK; i += TBA) {
        int gi = base + i;
        if (gi < N) {
            unsigned d = 1u + agent_ld_u(&tdeg[gi]);   // self loop
            float rr = 1.0f / sqrtf((float)d);
            dis[gi] = rr;
            y[gi] = x[gi] * rr;
        }
    }
}

// ---------------- K3: gather y totals + fused prep2 (z) ----------------
__global__ __launch_bounds__(TBA) void gacc1_k(
        const unsigned* __restrict__ packedB, const unsigned* __restrict__ gcur,
        const float* __restrict__ val /* y */, int cap, int capS,
        float* __restrict__ tsum, unsigned* __restrict__ ctr,
        const float* __restrict__ dis,
        const float* __restrict__ W1, const float* __restrict__ b1,
        const float* __restrict__ W2, float* __restrict__ z, int N) {
    __shared__ float acc[SBK];
    __shared__ float sW1[256], sb1[256], sW2[256];
    for (int i = threadIdx.x; i < SBK; i += TBA) acc[i] = 0.0f;
    __syncthreads();
    int b = blockIdx.x >> 4, set = blockIdx.x & 15;
    unsigned cnt = min(gcur[(b * NSET + set) * GSTRIDE], (unsigned)capS);
    const unsigned* p = packedB + (size_t)b * cap + (size_t)set * capS;
    const uint4* p4 = (const uint4*)p;
    unsigned nq = cnt >> 2;
    unsigned qi = threadIdx.x;
    for (; qi + TBA < nq; qi += 2 * TBA) {
        uint4 a = p4[qi], c = p4[qi + TBA];
        float v0 = val[a.x & 0x1FFFFu], v1 = val[a.y & 0x1FFFFu];
        float v2 = val[a.z & 0x1FFFFu], v3 = val[a.w & 0x1FFFFu];
        float v4 = val[c.x & 0x1FFFFu], v5 = val[c.y & 0x1FFFFu];
        float v6 = val[c.z & 0x1FFFFu], v7 = val[c.w & 0x1FFFFu];
        lds_addf(&acc[a.x >> 17], v0); lds_addf(&acc[a.y >> 17], v1);
        lds_addf(&acc[a.z >> 17], v2); lds_addf(&acc[a.w >> 17], v3);
        lds_addf(&acc[c.x >> 17], v4); lds_addf(&acc[c.y >> 17], v5);
        lds_addf(&acc[c.z >> 17], v6); lds_addf(&acc[c.w >> 17], v7);
    }
    for (; qi < nq; qi += TBA) {
        uint4 a = p4[qi];
        float v0 = val[a.x & 0x1FFFFu], v1 = val[a.y & 0x1FFFFu];
        float v2 = val[a.z & 0x1FFFFu], v3 = val[a.w & 0x1FFFFu];
        lds_addf(&acc[a.x >> 17], v0); lds_addf(&acc[a.y >> 17], v1);
        lds_addf(&acc[a.z >> 17], v2); lds_addf(&acc[a.w >> 17], v3);
    }
    for (unsigned j = (nq << 2) + threadIdx.x; j < cnt; j += TBA) {
        unsigned pk = p[j];
        lds_addf(&acc[pk >> 17], val[pk & 0x1FFFFu]);
    }
    __syncthreads();
    int base = b << SB_BITS;
    for (int i = threadIdx.x; i < SBK; i += TBA) {
        float v = acc[i];
        if (v != 0.0f) atomicAdd(&tsum[base + i], v);
    }

    // ---- fused prep2: last block of this bucket computes z ----
    if (!claim_last(&ctr[b])) return;
    for (int j = threadIdx.x; j < 256; j += TBA) {
        sW1[j] = W1[j]; sb1[j] = b1[j]; sW2[j] = W2[j];
    }
    __syncthreads();
    const float4* w1v = (const float4*)sW1;
    const float4* b1v = (const float4*)sb1;
    const float4* w2v = (const float4*)sW2;
    for (int i = threadIdx.x; i < SBK; i += TBA) {
        int gi = base + i;
        if (gi < N) {
            float tt = agent_ld_f(&tsum[gi]);
            float rr = dis[gi];
            float s = rr * (tt + val[gi]);
            float g = 0.0f;
            #pragma unroll 8
            for (int jj = 0; jj < 64; jj++) {   // H=256 -> 64 quads
                float4 a = w1v[jj], bb = b1v[jj], c = w2v[jj];
                float h0 = fmaf(s, a.x, bb.x); h0 = h0 > 0.0f ? h0 : 0.0f;
                float h1 = fmaf(s, a.y, bb.y); h1 = h1 > 0.0f ? h1 : 0.0f;
                float h2 = fmaf(s, a.z, bb.z); h2 = h2 > 0.0f ? h2 : 0.0f;
                float h3 = fmaf(s, a.w, bb.w); h3 = h3 > 0.0f ? h3 : 0.0f;
                g = fmaf(h0, c.x, g); g = fmaf(h1, c.y, g);
                g = fmaf(h2, c.z, g); g = fmaf(h3, c.w, g);
            }
            z[gi] = g * rr;
        }
    }
}

// ---------------- K4: gather z totals + fused finout ----------------
__global__ __launch_bounds__(TBA) void gacc2_k(
        const unsigned* __restrict__ packedB, const unsigned* __restrict__ gcur,
        const float* __restrict__ val /* z */, int cap, int capS,
        float* __restrict__ tsum, unsigned* __restrict__ ctr,
        const float* __restrict__ dis, const float* __restrict__ b2,
        float* __restrict__ out, int N) {
    __shared__ float acc[SBK];
    for (int i = threadIdx.x; i < SBK; i += TBA) acc[i] = 0.0f;
    __syncthreads();
    int b = blockIdx.x >> 4, set = blockIdx.x & 15;
    unsigned cnt = min(gcur[(b * NSET + set) * GSTRIDE], (unsigned)capS);
    const unsigned* p = packedB + (size_t)b * cap + (size_t)set * capS;
    const uint4* p4 = (const uint4*)p;
    unsigned nq = cnt >> 2;
    unsigned qi = threadIdx.x;
    for (; qi + TBA < nq; qi += 2 * TBA) {
        uint4 a = p4[qi], c = p4[qi + TBA];
        float v0 = val[a.x & 0x1FFFFu], v1 = val[a.y & 0x1FFFFu];
        float v2 = val[a.z & 0x1FFFFu], v3 = val[a.w & 0x1FFFFu];
        float v4 = val[c.x & 0x1FFFFu], v5 = val[c.y & 0x1FFFFu];
        float v6 = val[c.z & 0x1FFFFu], v7 = val[c.w & 0x1FFFFu];
        lds_addf(&acc[a.x >> 17], v0); lds_addf(&acc[a.y >> 17], v1);
        lds_addf(&acc[a.z >> 17], v2); lds_addf(&acc[a.w >> 17], v3);
        lds_addf(&acc[c.x >> 17], v4); lds_addf(&acc[c.y >> 17], v5);
        lds_addf(&acc[c.z >> 17], v6); lds_addf(&acc[c.w >> 17], v7);
    }
    for (; qi < nq; qi += TBA) {
        uint4 a = p4[qi];
        float v0 = val[a.x & 0x1FFFFu], v1 = val[a.y & 0x1FFFFu];
        float v2 = val[a.z & 0x1FFFFu], v3 = val[a.w & 0x1FFFFu];
        lds_addf(&acc[a.x >> 17], v0); lds_addf(&acc[a.y >> 17], v1);
        lds_addf(&acc[a.z >> 17], v2); lds_addf(&acc[a.w >> 17], v3);
    }
    for (unsigned j = (nq << 2) + threadIdx.x; j < cnt; j += TBA) {
        unsigned pk = p[j];
        lds_addf(&acc[pk >> 17], val[pk & 0x1FFFFu]);
    }
    __syncthreads();
    int base = b << SB_BITS;
    for (int i = threadIdx.x; i < SBK; i += TBA) {
        float v = acc[i];
        if (v != 0.0f) atomicAdd(&tsum[base + i], v);
    }

    // ---- fused finout: last block of this bucket writes out ----
    if (!claim_last(&ctr[b])) return;
    float bb2 = b2[0];
    for (int i = threadIdx.x; i < SBK; i += TBA) {
        int gi = base + i;
        if (gi < N) {
            float u = agent_ld_f(&tsum[gi]);
            out[gi] = dis[gi] * (u + val[gi]) + bb2;
        }
    }
}

extern "C" void kernel_launch(void* const* d_in, const int* in_sizes, int n_in,
                              void* d_out, int out_size, void* d_ws, size_t ws_size,
                              hipStream_t stream) {
    const float* x   = (const float*)d_in[0];
    const int*   ei  = (const int*)d_in[1];     // int32 (JAX x64-off)
    const float* W1  = (const float*)d_in[2];
    const float* b1  = (const float*)d_in[3];
    const float* W2  = (const float*)d_in[4];
    const float* b2  = (const float*)d_in[5];
    float*       out = (float*)d_out;

    const int N = in_sizes[0];        // 100000
    const int E = in_sizes[1] / 2;    // 3200000

    const int* srcp = ei;
    const int* dstp = ei + E;

    const int NB   = (N + SBK - 1) >> SB_BITS;              // 49
    const int PLN  = NB * SBK;                              // 100352
    const int capS = (E / (NB * NSET) + 1536 + 7) & ~7;     // ~24 sigma, 8-aligned
    const int cap  = capS * NSET;

    // workspace (u32 units), zero-init region first:
    // [gcur 8192][ctr 256][tdeg PLN][ty PLN][tz PLN] | [dis N][y N][z N][packedB]
    unsigned* W    = (unsigned*)d_ws;
    unsigned* gcur = W;
    unsigned* ctr  = W + 8192;                                // 3 stages x 64
    unsigned* tdeg = W + 8448;
    float*    ty   = (float*)(W + 8448 + (size_t)PLN);
    float*    tz   = (float*)(W + 8448 + (size_t)2 * PLN);
    float*    dis  = (float*)(W + 8448 + (size_t)3 * PLN);
    float*    y    = (float*)(W + 8448 + (size_t)3 * PLN + (size_t)N);
    float*    z    = (float*)(W + 8448 + (size_t)3 * PLN + (size_t)2 * N);
    unsigned* packedB = W + 8448 + (size_t)3 * PLN + (size_t)3 * N;

    hipMemsetAsync(gcur, 0, (8448 + (size_t)3 * PLN) * sizeof(unsigned), stream);

    const int gA = NB * NSET;   // 784

    part_k <<<NAPB, TBP, 0, stream>>>(srcp, dstp, E, cap, capS, gcur, packedB);
    degp_k <<<gA, TBA, 0, stream>>>(packedB, gcur, cap, capS, tdeg,
                                    ctr, x, N, dis, y);
    gacc1_k<<<gA, TBA, 0, stream>>>(packedB, gcur, y, cap, capS,
                                    ty, ctr + 64, dis, W1, b1, W2, z, N);
    gacc2_k<<<gA, TBA, 0, stream>>>(packedB, gcur, z, cap, capS,
                                    tz, ctr + 128, dis, b2, out, N);
}

// Round 3
// 162.640 us; speedup vs baseline: 2.9668x; 1.2521x over previous
//
#include <hip/hip_runtime.h>

// 2-layer GCN collapsed to scalar per-node quantities (verified R2):
//   dis = 1/sqrt(deg+1);  y = x*dis;  t[d] = sum_{e->d} y[src]
//   s = dis*(t+y);  z = dis * sum_j relu(s*W1[j]+b1[j])*W2[j]
//   out[d] = dis[d]*(sum_{e->d} z[src] + z[d]) + b2
//
// R15: single-owner buckets. R14's 78us gacc1_k was 1.6M device-scope float
// atomics with 16-way same-address contention (fabric RMW serialization).
// Fix: SBK 2048->512 (NB=196 buckets); ONE block owns a bucket and reads all
// 16 set-regions into its LDS accumulator, then applies the node epilogue
// directly from LDS. No partial rows, no global atomics, no claim counters,
// no fences. 5 dispatches. part_k gets a 256-entry histogram + block-wide
// scan (MAXB must equal TBP).

#define SB_BITS 9
#define SBK     512           // nodes per bucket
#define MAXB    256           // histogram size == TBP (1 bucket/thread)
#define TBP     256           // part_k block size
#define NAPB    1024          // part_k grid (64 blocks per set)
#define TPT     4096          // part_k tile (16 edges/thread)
#define KPT     16
#define NW      4             // waves per part_k block
#define NSET    16            // independent cursor/region sets
#define GSTRIDE 8             // u32 stride between cursors (32B granule)
#define TBA     512           // aggregation block size (8 waves)

__device__ inline void lds_addf(float* p, float v) {
    __hip_atomic_fetch_add(p, v, __ATOMIC_RELAXED, __HIP_MEMORY_SCOPE_WORKGROUP);
}

// ---------------- K1: partition ----------------
__global__ __launch_bounds__(TBP) void part_k(
        const int* __restrict__ src, const int* __restrict__ dst, int E,
        int cap, int capS, unsigned* __restrict__ gcur,
        unsigned* __restrict__ packedB) {
    __shared__ unsigned sp[TPT];
    __shared__ unsigned char sbk[TPT];
    __shared__ unsigned woff[NW][MAXB];
    __shared__ unsigned cnt2[NW][MAXB];
    __shared__ unsigned scn[MAXB];
    __shared__ unsigned gbase[MAXB];
    __shared__ unsigned wtot[NW];
    const int t = threadIdx.x;
    const int w = t >> 6;
    const int lane = t & 63;
    const int set = blockIdx.x & (NSET - 1);
    int CH = (E + (int)gridDim.x - 1) / (int)gridDim.x;
    int cs = blockIdx.x * CH;
    int ce = min(cs + CH, E);
    for (int ts = cs; ts < ce; ts += TPT) {
        int tcnt = min(TPT, ce - ts);
        // zero histograms (MAXB == TBP: one bucket per thread)
        #pragma unroll
        for (int ww = 0; ww < NW; ww++) { woff[ww][t] = 0u; cnt2[ww][t] = 0u; }
        __syncthreads();
        unsigned es[KPT], ed[KPT]; int nk = 0;
        #pragma unroll
        for (int k = 0; k < KPT; k++) {
            int j = ts + t + k * TBP;
            if (j < ce) {
                es[k] = (unsigned)src[j];
                ed[k] = (unsigned)dst[j];
                atomicAdd(&woff[w][ed[k] >> SB_BITS], 1u);
                nk = k + 1;
            }
        }
        __syncthreads();
        // per-bucket totals -> wave offsets, global cursor, block-wide scan
        unsigned h0 = woff[0][t], h1 = woff[1][t], h2 = woff[2][t], h3 = woff[3][t];
        woff[0][t] = 0u; woff[1][t] = h0; woff[2][t] = h0 + h1;
        woff[3][t] = h0 + h1 + h2;
        unsigned th = h0 + h1 + h2 + h3;
        gbase[t] = th ? atomicAdd(&gcur[(t * NSET + set) * GSTRIDE], th) : 0u;
        unsigned v = th;
        #pragma unroll
        for (int off = 1; off < 64; off <<= 1) {
            unsigned u = __shfl_up(v, off, 64);
            if (lane >= off) v += u;
        }
        if (lane == 63) wtot[w] = v;
        __syncthreads();
        unsigned wpre = 0;
        #pragma unroll
        for (int ww = 0; ww < NW; ww++) wpre += (ww < w) ? wtot[ww] : 0u;
        scn[t] = wpre + v - th;        // block-exclusive base for bucket t
        __syncthreads();
        for (int k = 0; k < nk; k++) {
            unsigned b = ed[k] >> SB_BITS;
            unsigned r = scn[b] + woff[w][b] + atomicAdd(&cnt2[w][b], 1u);
            sp[r]  = es[k] | ((ed[k] & (SBK - 1u)) << 17);
            sbk[r] = (unsigned char)b;
        }
        __syncthreads();
        #pragma unroll
        for (int k = 0; k < KPT; k++) {
            int j2 = t + k * TBP;
            if (j2 < tcnt) {
                unsigned b = sbk[j2];
                unsigned gpos = gbase[b] + (unsigned)j2 - scn[b];
                if (gpos < (unsigned)capS)
                    packedB[(size_t)b * cap + (size_t)set * capS + gpos] = sp[j2];
            }
        }
        __syncthreads();
    }
}

// ---------------- K2: degree (whole bucket) + prep1 (dis, y) ----------------
__global__ __launch_bounds__(TBA) void degp_k(
        const unsigned* __restrict__ packedB, const unsigned* __restrict__ gcur,
        int cap, int capS, const float* __restrict__ x, int N,
        float* __restrict__ dis, float* __restrict__ y) {
    __shared__ unsigned acc[SBK];
    for (int i = threadIdx.x; i < SBK; i += TBA) acc[i] = 0u;
    __syncthreads();
    const int b = blockIdx.x;
    const unsigned* pb = packedB + (size_t)b * cap;
    for (int set = 0; set < NSET; set++) {
        unsigned cnt = min(gcur[(b * NSET + set) * GSTRIDE], (unsigned)capS);
        const unsigned* p = pb + (size_t)set * capS;
        const uint4* p4 = (const uint4*)p;
        unsigned nq = cnt >> 2;
        for (unsigned qi = threadIdx.x; qi < nq; qi += TBA) {
            uint4 a = p4[qi];
            atomicAdd(&acc[a.x >> 17], 1u); atomicAdd(&acc[a.y >> 17], 1u);
            atomicAdd(&acc[a.z >> 17], 1u); atomicAdd(&acc[a.w >> 17], 1u);
        }
        for (unsigned j = (nq << 2) + threadIdx.x; j < cnt; j += TBA)
            atomicAdd(&acc[p[j] >> 17], 1u);
    }
    __syncthreads();
    const int base = b << SB_BITS;
    for (int i = threadIdx.x; i < SBK; i += TBA) {
        int gi = base + i;
        if (gi < N) {
            float rr = 1.0f / sqrtf((float)(1u + acc[i]));   // +1 self loop
            dis[gi] = rr;
            y[gi] = x[gi] * rr;
        }
    }
}

// ---------------- K3: gather y (whole bucket) + prep2 (z) ----------------
__global__ __launch_bounds__(TBA) void gacc1_k(
        const unsigned* __restrict__ packedB, const unsigned* __restrict__ gcur,
        const float* __restrict__ val /* y */, int cap, int capS,
        const float* __restrict__ dis,
        const float* __restrict__ W1, const float* __restrict__ b1,
        const float* __restrict__ W2, float* __restrict__ z, int N) {
    __shared__ float acc[SBK];
    __shared__ float sW1[256], sb1[256], sW2[256];
    if (threadIdx.x < 256) {
        sW1[threadIdx.x] = W1[threadIdx.x];
        sb1[threadIdx.x] = b1[threadIdx.x];
        sW2[threadIdx.x] = W2[threadIdx.x];
    }
    for (int i = threadIdx.x; i < SBK; i += TBA) acc[i] = 0.0f;
    __syncthreads();
    const int b = blockIdx.x;
    const unsigned* pb = packedB + (size_t)b * cap;
    for (int set = 0; set < NSET; set++) {
        unsigned cnt = min(gcur[(b * NSET + set) * GSTRIDE], (unsigned)capS);
        const unsigned* p = pb + (size_t)set * capS;
        const uint4* p4 = (const uint4*)p;
        unsigned nq = cnt >> 2;
        for (unsigned qi = threadIdx.x; qi < nq; qi += TBA) {
            uint4 a = p4[qi];
            float v0 = val[a.x & 0x1FFFFu], v1 = val[a.y & 0x1FFFFu];
            float v2 = val[a.z & 0x1FFFFu], v3 = val[a.w & 0x1FFFFu];
            lds_addf(&acc[a.x >> 17], v0); lds_addf(&acc[a.y >> 17], v1);
            lds_addf(&acc[a.z >> 17], v2); lds_addf(&acc[a.w >> 17], v3);
        }
        for (unsigned j = (nq << 2) + threadIdx.x; j < cnt; j += TBA) {
            unsigned pk = p[j];
            lds_addf(&acc[pk >> 17], val[pk & 0x1FFFFu]);
        }
    }
    __syncthreads();
    const int base = b << SB_BITS;
    const float4* w1v = (const float4*)sW1;
    const float4* b1v = (const float4*)sb1;
    const float4* w2v = (const float4*)sW2;
    for (int i = threadIdx.x; i < SBK; i += TBA) {
        int gi = base + i;
        if (gi < N) {
            float tt = acc[i];
            float rr = dis[gi];
            float s = rr * (tt + val[gi]);
            float g = 0.0f;
            #pragma unroll 8
            for (int jj = 0; jj < 64; jj++) {   // H=256 -> 64 quads
                float4 a = w1v[jj], bb = b1v[jj], c = w2v[jj];
                float h0 = fmaf(s, a.x, bb.x); h0 = h0 > 0.0f ? h0 : 0.0f;
                float h1 = fmaf(s, a.y, bb.y); h1 = h1 > 0.0f ? h1 : 0.0f;
                float h2 = fmaf(s, a.z, bb.z); h2 = h2 > 0.0f ? h2 : 0.0f;
                float h3 = fmaf(s, a.w, bb.w); h3 = h3 > 0.0f ? h3 : 0.0f;
                g = fmaf(h0, c.x, g); g = fmaf(h1, c.y, g);
                g = fmaf(h2, c.z, g); g = fmaf(h3, c.w, g);
            }
            z[gi] = g * rr;
        }
    }
}

// ---------------- K4: gather z (whole bucket) + finout ----------------
__global__ __launch_bounds__(TBA) void gacc2_k(
        const unsigned* __restrict__ packedB, const unsigned* __restrict__ gcur,
        const float* __restrict__ val /* z */, int cap, int capS,
        const float* __restrict__ dis, const float* __restrict__ b2,
        float* __restrict__ out, int N) {
    __shared__ float acc[SBK];
    for (int i = threadIdx.x; i < SBK; i += TBA) acc[i] = 0.0f;
    __syncthreads();
    const int b = blockIdx.x;
    const unsigned* pb = packedB + (size_t)b * cap;
    for (int set = 0; set < NSET; set++) {
        unsigned cnt = min(gcur[(b * NSET + set) * GSTRIDE], (unsigned)capS);
        const unsigned* p = pb + (size_t)set * capS;
        const uint4* p4 = (const uint4*)p;
        unsigned nq = cnt >> 2;
        for (unsigned qi = threadIdx.x; qi < nq; qi += TBA) {
            uint4 a = p4[qi];
            float v0 = val[a.x & 0x1FFFFu], v1 = val[a.y & 0x1FFFFu];
            float v2 = val[a.z & 0x1FFFFu], v3 = val[a.w & 0x1FFFFu];
            lds_addf(&acc[a.x >> 17], v0); lds_addf(&acc[a.y >> 17], v1);
            lds_addf(&acc[a.z >> 17], v2); lds_addf(&acc[a.w >> 17], v3);
        }
        for (unsigned j = (nq << 2) + threadIdx.x; j < cnt; j += TBA) {
            unsigned pk = p[j];
            lds_addf(&acc[pk >> 17], val[pk & 0x1FFFFu]);
        }
    }
    __syncthreads();
    const int base = b << SB_BITS;
    float bb2 = b2[0];
    for (int i = threadIdx.x; i < SBK; i += TBA) {
        int gi = base + i;
        if (gi < N) {
            out[gi] = dis[gi] * (acc[i] + val[gi]) + bb2;
        }
    }
}

extern "C" void kernel_launch(void* const* d_in, const int* in_sizes, int n_in,
                              void* d_out, int out_size, void* d_ws, size_t ws_size,
                              hipStream_t stream) {
    const float* x   = (const float*)d_in[0];
    const int*   ei  = (const int*)d_in[1];     // int32 (JAX x64-off)
    const float* W1  = (const float*)d_in[2];
    const float* b1  = (const float*)d_in[3];
    const float* W2  = (const float*)d_in[4];
    const float* b2  = (const float*)d_in[5];
    float*       out = (float*)d_out;

    const int N = in_sizes[0];        // 100000
    const int E = in_sizes[1] / 2;    // 3200000

    const int* srcp = ei;
    const int* dstp = ei + E;

    const int NB   = (N + SBK - 1) >> SB_BITS;            // 196
    const int capS = (E / (NB * NSET) + 384 + 7) & ~7;    // ~12 sigma slack
    const int cap  = capS * NSET;
    const int NCUR = NB * NSET * GSTRIDE;                 // 25088 u32

    // workspace (u32 units):
    // [gcur NCUR][dis N][y N][z N][packedB NB*cap]
    unsigned* W    = (unsigned*)d_ws;
    unsigned* gcur = W;
    float*    dis  = (float*)(W + (size_t)NCUR);
    float*    y    = (float*)(W + (size_t)NCUR + (size_t)N);
    float*    z    = (float*)(W + (size_t)NCUR + (size_t)2 * N);
    unsigned* packedB = W + (size_t)NCUR + (size_t)3 * N; // 16B-aligned (N%4==0)

    hipMemsetAsync(gcur, 0, (size_t)NCUR * sizeof(unsigned), stream);

    part_k <<<NAPB, TBP, 0, stream>>>(srcp, dstp, E, cap, capS, gcur, packedB);
    degp_k <<<NB, TBA, 0, stream>>>(packedB, gcur, cap, capS, x, N, dis, y);
    gacc1_k<<<NB, TBA, 0, stream>>>(packedB, gcur, y, cap, capS, dis,
                                    W1, b1, W2, z, N);
    gacc2_k<<<NB, TBA, 0, stream>>>(packedB, gcur, z, cap, capS, dis, b2, out, N);
}

// Round 4
// 153.478 us; speedup vs baseline: 3.1439x; 1.0597x over previous
//
#include <hip/hip_runtime.h>

// 2-layer GCN collapsed to scalar per-node quantities (verified R2):
//   dis = 1/sqrt(deg+1);  y = x*dis;  t[d] = sum_{e->d} y[src]
//   s = dis*(t+y);  z = dis * sum_j relu(s*W1[j]+b1[j])*W2[j]
//   out[d] = dis[d]*(sum_{e->d} z[src] + z[d]) + b2
//
// R16: single-variable vs R15 — aggregation blocks 512 -> 1024 threads with
// wave-per-set decomposition (wave w drains set-region w; no per-set serial
// loop, no idle threads, 16 waves/CU instead of 8). R15's agg kernels were
// latency-bound: 196 blocks x 8 waves on 196/256 CUs, dependent
// load->gather->LDS-atomic chains. part_k and workspace layout unchanged.

#define SB_BITS 9
#define SBK     512           // nodes per bucket
#define MAXB    256           // histogram size == TBP (1 bucket/thread)
#define TBP     256           // part_k block size
#define NAPB    1024          // part_k grid (64 blocks per set)
#define TPT     4096          // part_k tile (16 edges/thread)
#define KPT     16
#define NW      4             // waves per part_k block
#define NSET    16            // independent cursor/region sets
#define GSTRIDE 8             // u32 stride between cursors (32B granule)
#define TBA     1024          // aggregation block size (16 waves = 16 sets)

__device__ inline void lds_addf(float* p, float v) {
    __hip_atomic_fetch_add(p, v, __ATOMIC_RELAXED, __HIP_MEMORY_SCOPE_WORKGROUP);
}

// ---------------- K1: partition ----------------
__global__ __launch_bounds__(TBP) void part_k(
        const int* __restrict__ src, const int* __restrict__ dst, int E,
        int cap, int capS, unsigned* __restrict__ gcur,
        unsigned* __restrict__ packedB) {
    __shared__ unsigned sp[TPT];
    __shared__ unsigned char sbk[TPT];
    __shared__ unsigned woff[NW][MAXB];
    __shared__ unsigned cnt2[NW][MAXB];
    __shared__ unsigned scn[MAXB];
    __shared__ unsigned gbase[MAXB];
    __shared__ unsigned wtot[NW];
    const int t = threadIdx.x;
    const int w = t >> 6;
    const int lane = t & 63;
    const int set = blockIdx.x & (NSET - 1);
    int CH = (E + (int)gridDim.x - 1) / (int)gridDim.x;
    int cs = blockIdx.x * CH;
    int ce = min(cs + CH, E);
    for (int ts = cs; ts < ce; ts += TPT) {
        int tcnt = min(TPT, ce - ts);
        // zero histograms (MAXB == TBP: one bucket per thread)
        #pragma unroll
        for (int ww = 0; ww < NW; ww++) { woff[ww][t] = 0u; cnt2[ww][t] = 0u; }
        __syncthreads();
        unsigned es[KPT], ed[KPT]; int nk = 0;
        #pragma unroll
        for (int k = 0; k < KPT; k++) {
            int j = ts + t + k * TBP;
            if (j < ce) {
                es[k] = (unsigned)src[j];
                ed[k] = (unsigned)dst[j];
                atomicAdd(&woff[w][ed[k] >> SB_BITS], 1u);
                nk = k + 1;
            }
        }
        __syncthreads();
        // per-bucket totals -> wave offsets, global cursor, block-wide scan
        unsigned h0 = woff[0][t], h1 = woff[1][t], h2 = woff[2][t], h3 = woff[3][t];
        woff[0][t] = 0u; woff[1][t] = h0; woff[2][t] = h0 + h1;
        woff[3][t] = h0 + h1 + h2;
        unsigned th = h0 + h1 + h2 + h3;
        gbase[t] = th ? atomicAdd(&gcur[(t * NSET + set) * GSTRIDE], th) : 0u;
        unsigned v = th;
        #pragma unroll
        for (int off = 1; off < 64; off <<= 1) {
            unsigned u = __shfl_up(v, off, 64);
            if (lane >= off) v += u;
        }
        if (lane == 63) wtot[w] = v;
        __syncthreads();
        unsigned wpre = 0;
        #pragma unroll
        for (int ww = 0; ww < NW; ww++) wpre += (ww < w) ? wtot[ww] : 0u;
        scn[t] = wpre + v - th;        // block-exclusive base for bucket t
        __syncthreads();
        for (int k = 0; k < nk; k++) {
            unsigned b = ed[k] >> SB_BITS;
            unsigned r = scn[b] + woff[w][b] + atomicAdd(&cnt2[w][b], 1u);
            sp[r]  = es[k] | ((ed[k] & (SBK - 1u)) << 17);
            sbk[r] = (unsigned char)b;
        }
        __syncthreads();
        #pragma unroll
        for (int k = 0; k < KPT; k++) {
            int j2 = t + k * TBP;
            if (j2 < tcnt) {
                unsigned b = sbk[j2];
                unsigned gpos = gbase[b] + (unsigned)j2 - scn[b];
                if (gpos < (unsigned)capS)
                    packedB[(size_t)b * cap + (size_t)set * capS + gpos] = sp[j2];
            }
        }
        __syncthreads();
    }
}

// ---------------- K2: degree (wave-per-set) + prep1 (dis, y) ----------------
__global__ __launch_bounds__(TBA) void degp_k(
        const unsigned* __restrict__ packedB, const unsigned* __restrict__ gcur,
        int cap, int capS, const float* __restrict__ x, int N,
        float* __restrict__ dis, float* __restrict__ y) {
    __shared__ unsigned acc[SBK];
    if (threadIdx.x < SBK) acc[threadIdx.x] = 0u;
    __syncthreads();
    const int b = blockIdx.x;
    const int w = threadIdx.x >> 6;      // wave = set
    const int lane = threadIdx.x & 63;
    unsigned cnt = min(gcur[(b * NSET + w) * GSTRIDE], (unsigned)capS);
    const unsigned* p = packedB + (size_t)b * cap + (size_t)w * capS;
    const uint4* p4 = (const uint4*)p;
    unsigned nq = cnt >> 2;
    unsigned qi = lane;
    for (; qi + 64 < nq; qi += 128) {
        uint4 a = p4[qi], c = p4[qi + 64];
        atomicAdd(&acc[a.x >> 17], 1u); atomicAdd(&acc[a.y >> 17], 1u);
        atomicAdd(&acc[a.z >> 17], 1u); atomicAdd(&acc[a.w >> 17], 1u);
        atomicAdd(&acc[c.x >> 17], 1u); atomicAdd(&acc[c.y >> 17], 1u);
        atomicAdd(&acc[c.z >> 17], 1u); atomicAdd(&acc[c.w >> 17], 1u);
    }
    for (; qi < nq; qi += 64) {
        uint4 a = p4[qi];
        atomicAdd(&acc[a.x >> 17], 1u); atomicAdd(&acc[a.y >> 17], 1u);
        atomicAdd(&acc[a.z >> 17], 1u); atomicAdd(&acc[a.w >> 17], 1u);
    }
    for (unsigned j = (nq << 2) + lane; j < cnt; j += 64)
        atomicAdd(&acc[p[j] >> 17], 1u);
    __syncthreads();
    const int base = b << SB_BITS;
    if (threadIdx.x < SBK) {
        int gi = base + threadIdx.x;
        if (gi < N) {
            float rr = 1.0f / sqrtf((float)(1u + acc[threadIdx.x]));  // +1 self loop
            dis[gi] = rr;
            y[gi] = x[gi] * rr;
        }
    }
}

// ---------------- K3: gather y (wave-per-set) + prep2 (z) ----------------
__global__ __launch_bounds__(TBA) void gacc1_k(
        const unsigned* __restrict__ packedB, const unsigned* __restrict__ gcur,
        const float* __restrict__ val /* y */, int cap, int capS,
        const float* __restrict__ dis,
        const float* __restrict__ W1, const float* __restrict__ b1,
        const float* __restrict__ W2, float* __restrict__ z, int N) {
    __shared__ float acc[SBK];
    __shared__ float sW1[256], sb1[256], sW2[256];
    if (threadIdx.x < 256) {
        sW1[threadIdx.x] = W1[threadIdx.x];
        sb1[threadIdx.x] = b1[threadIdx.x];
        sW2[threadIdx.x] = W2[threadIdx.x];
    }
    if (threadIdx.x < SBK) acc[threadIdx.x] = 0.0f;
    __syncthreads();
    const int b = blockIdx.x;
    const int w = threadIdx.x >> 6;
    const int lane = threadIdx.x & 63;
    unsigned cnt = min(gcur[(b * NSET + w) * GSTRIDE], (unsigned)capS);
    const unsigned* p = packedB + (size_t)b * cap + (size_t)w * capS;
    const uint4* p4 = (const uint4*)p;
    unsigned nq = cnt >> 2;
    unsigned qi = lane;
    for (; qi + 64 < nq; qi += 128) {
        uint4 a = p4[qi], c = p4[qi + 64];
        float v0 = val[a.x & 0x1FFFFu], v1 = val[a.y & 0x1FFFFu];
        float v2 = val[a.z & 0x1FFFFu], v3 = val[a.w & 0x1FFFFu];
        float v4 = val[c.x & 0x1FFFFu], v5 = val[c.y & 0x1FFFFu];
        float v6 = val[c.z & 0x1FFFFu], v7 = val[c.w & 0x1FFFFu];
        lds_addf(&acc[a.x >> 17], v0); lds_addf(&acc[a.y >> 17], v1);
        lds_addf(&acc[a.z >> 17], v2); lds_addf(&acc[a.w >> 17], v3);
        lds_addf(&acc[c.x >> 17], v4); lds_addf(&acc[c.y >> 17], v5);
        lds_addf(&acc[c.z >> 17], v6); lds_addf(&acc[c.w >> 17], v7);
    }
    for (; qi < nq; qi += 64) {
        uint4 a = p4[qi];
        float v0 = val[a.x & 0x1FFFFu], v1 = val[a.y & 0x1FFFFu];
        float v2 = val[a.z & 0x1FFFFu], v3 = val[a.w & 0x1FFFFu];
        lds_addf(&acc[a.x >> 17], v0); lds_addf(&acc[a.y >> 17], v1);
        lds_addf(&acc[a.z >> 17], v2); lds_addf(&acc[a.w >> 17], v3);
    }
    for (unsigned j = (nq << 2) + lane; j < cnt; j += 64) {
        unsigned pk = p[j];
        lds_addf(&acc[pk >> 17], val[pk & 0x1FFFFu]);
    }
    __syncthreads();
    const int base = b << SB_BITS;
    const float4* w1v = (const float4*)sW1;
    const float4* b1v = (const float4*)sb1;
    const float4* w2v = (const float4*)sW2;
    if (threadIdx.x < SBK) {
        int gi = base + threadIdx.x;
        if (gi < N) {
            float tt = acc[threadIdx.x];
            float rr = dis[gi];
            float s = rr * (tt + val[gi]);
            float g = 0.0f;
            #pragma unroll 8
            for (int jj = 0; jj < 64; jj++) {   // H=256 -> 64 quads
                float4 a = w1v[jj], bb = b1v[jj], c = w2v[jj];
                float h0 = fmaf(s, a.x, bb.x); h0 = h0 > 0.0f ? h0 : 0.0f;
                float h1 = fmaf(s, a.y, bb.y); h1 = h1 > 0.0f ? h1 : 0.0f;
                float h2 = fmaf(s, a.z, bb.z); h2 = h2 > 0.0f ? h2 : 0.0f;
                float h3 = fmaf(s, a.w, bb.w); h3 = h3 > 0.0f ? h3 : 0.0f;
                g = fmaf(h0, c.x, g); g = fmaf(h1, c.y, g);
                g = fmaf(h2, c.z, g); g = fmaf(h3, c.w, g);
            }
            z[gi] = g * rr;
        }
    }
}

// ---------------- K4: gather z (wave-per-set) + finout ----------------
__global__ __launch_bounds__(TBA) void gacc2_k(
        const unsigned* __restrict__ packedB, const unsigned* __restrict__ gcur,
        const float* __restrict__ val /* z */, int cap, int capS,
        const float* __restrict__ dis, const float* __restrict__ b2,
        float* __restrict__ out, int N) {
    __shared__ float acc[SBK];
    if (threadIdx.x < SBK) acc[threadIdx.x] = 0.0f;
    __syncthreads();
    const int b = blockIdx.x;
    const int w = threadIdx.x >> 6;
    const int lane = threadIdx.x & 63;
    unsigned cnt = min(gcur[(b * NSET + w) * GSTRIDE], (unsigned)capS);
    const unsigned* p = packedB + (size_t)b * cap + (size_t)w * capS;
    const uint4* p4 = (const uint4*)p;
    unsigned nq = cnt >> 2;
    unsigned qi = lane;
    for (; qi + 64 < nq; qi += 128) {
        uint4 a = p4[qi], c = p4[qi + 64];
        float v0 = val[a.x & 0x1FFFFu], v1 = val[a.y & 0x1FFFFu];
        float v2 = val[a.z & 0x1FFFFu], v3 = val[a.w & 0x1FFFFu];
        float v4 = val[c.x & 0x1FFFFu], v5 = val[c.y & 0x1FFFFu];
        float v6 = val[c.z & 0x1FFFFu], v7 = val[c.w & 0x1FFFFu];
        lds_addf(&acc[a.x >> 17], v0); lds_addf(&acc[a.y >> 17], v1);
        lds_addf(&acc[a.z >> 17], v2); lds_addf(&acc[a.w >> 17], v3);
        lds_addf(&acc[c.x >> 17], v4); lds_addf(&acc[c.y >> 17], v5);
        lds_addf(&acc[c.z >> 17], v6); lds_addf(&acc[c.w >> 17], v7);
    }
    for (; qi < nq; qi += 64) {
        uint4 a = p4[qi];
        float v0 = val[a.x & 0x1FFFFu], v1 = val[a.y & 0x1FFFFu];
        float v2 = val[a.z & 0x1FFFFu], v3 = val[a.w & 0x1FFFFu];
        lds_addf(&acc[a.x >> 17], v0); lds_addf(&acc[a.y >> 17], v1);
        lds_addf(&acc[a.z >> 17], v2); lds_addf(&acc[a.w >> 17], v3);
    }
    for (unsigned j = (nq << 2) + lane; j < cnt; j += 64) {
        unsigned pk = p[j];
        lds_addf(&acc[pk >> 17], val[pk & 0x1FFFFu]);
    }
    __syncthreads();
    const int base = b << SB_BITS;
    float bb2 = b2[0];
    if (threadIdx.x < SBK) {
        int gi = base + threadIdx.x;
        if (gi < N) {
            out[gi] = dis[gi] * (acc[threadIdx.x] + val[gi]) + bb2;
        }
    }
}

extern "C" void kernel_launch(void* const* d_in, const int* in_sizes, int n_in,
                              void* d_out, int out_size, void* d_ws, size_t ws_size,
                              hipStream_t stream) {
    const float* x   = (const float*)d_in[0];
    const int*   ei  = (const int*)d_in[1];     // int32 (JAX x64-off)
    const float* W1  = (const float*)d_in[2];
    const float* b1  = (const float*)d_in[3];
    const float* W2  = (const float*)d_in[4];
    const float* b2  = (const float*)d_in[5];
    float*       out = (float*)d_out;

    const int N = in_sizes[0];        // 100000
    const int E = in_sizes[1] / 2;    // 3200000

    const int* srcp = ei;
    const int* dstp = ei + E;

    const int NB   = (N + SBK - 1) >> SB_BITS;            // 196
    const int capS = (E / (NB * NSET) + 384 + 7) & ~7;    // ~12 sigma slack
    const int cap  = capS * NSET;
    const int NCUR = NB * NSET * GSTRIDE;                 // 25088 u32

    // workspace (u32 units):
    // [gcur NCUR][dis N][y N][z N][packedB NB*cap]
    unsigned* W    = (unsigned*)d_ws;
    unsigned* gcur = W;
    float*    dis  = (float*)(W + (size_t)NCUR);
    float*    y    = (float*)(W + (size_t)NCUR + (size_t)N);
    float*    z    = (float*)(W + (size_t)NCUR + (size_t)2 * N);
    unsigned* packedB = W + (size_t)NCUR + (size_t)3 * N; // 16B-aligned (N%4==0)

    hipMemsetAsync(gcur, 0, (size_t)NCUR * sizeof(unsigned), stream);

    part_k <<<NAPB, TBP, 0, stream>>>(srcp, dstp, E, cap, capS, gcur, packedB);
    degp_k <<<NB, TBA, 0, stream>>>(packedB, gcur, cap, capS, x, N, dis, y);
    gacc1_k<<<NB, TBA, 0, stream>>>(packedB, gcur, y, cap, capS, dis,
                                    W1, b1, W2, z, N);
    gacc2_k<<<NB, TBA, 0, stream>>>(packedB, gcur, z, cap, capS, dis, b2, out, N);
}